// Round 14
// baseline (647.040 us; speedup 1.0000x reference)
//
#include <hip/hip_runtime.h>
#include <hip/hip_bf16.h>

#define DNODE 59
#define NGRAPH 256
typedef __hip_bfloat16 bf16;
typedef long long ll;
typedef unsigned short ushort;
typedef short short8v __attribute__((ext_vector_type(8)));
typedef float float4v __attribute__((ext_vector_type(4)));

__device__ __forceinline__ float b2f(bf16 x) { return __bfloat162float(x); }
__device__ __forceinline__ float bs2f(ushort u) {
    return __uint_as_float(((unsigned int)u) << 16);
}
__device__ __forceinline__ float ldv(const void* p, ll i, int isf) {
    return isf ? ((const float*)p)[i] : b2f(((const bf16*)p)[i]);
}
__device__ __forceinline__ ushort f2bs(float x) {   // RNE
    unsigned int u = __float_as_uint(x);
    u += 0x7fffu + ((u >> 16) & 1u);
    return (ushort)(u >> 16);
}
__device__ __forceinline__ float frcp(float x) { return __builtin_amdgcn_rcpf(x); }
__device__ __forceinline__ float selu_f(float x) {
    const float scale = 1.0507009873554805f;
    const float alpha = 1.6732632423543772f;
    return x > 0.f ? scale * x : scale * alpha * (__expf(x) - 1.f);
}
__device__ __forceinline__ float fsigmoid(float x) { return frcp(1.f + __expf(-x)); }
__device__ __forceinline__ float ftanh(float x) {
    float t = __expf(-2.f * fabsf(x));
    return copysignf((1.f - t) * frcp(1.f + t), x);
}

// typed load (branch hoisted OUT of loops -> compiler can pipeline)
template <typename T>
__device__ __forceinline__ float ldT(const T* p, ll i);
template <> __device__ __forceinline__ float ldT<float>(const float* p, ll i) { return p[i]; }
template <> __device__ __forceinline__ float ldT<bf16>(const bf16* p, ll i)  { return b2f(p[i]); }

// ---------------- dtype detector (parallel) + gid-sort scratch zeroing -----------
__global__ void k_detect(const ushort* __restrict__ gsu, int* __restrict__ flag,
                         int* __restrict__ gcnt)
{
    __shared__ int wilds;
    int t = threadIdx.x;
    if (t == 0) wilds = 0;
    if (t < 512) gcnt[t] = 0;          // gcnt[256] + gpos[256]
    __syncthreads();
    int e = (gsu[t] >> 7) & 0xFF;      // 512 threads, one sample each
    if (e >= 0x8F) atomicAdd(&wilds, 1);
    __syncthreads();
    if (t == 0) *flag = (wilds >= 20) ? 1 : 0;
}

// ---------------- fused init + weight prep (one launch) --------------------------
__global__ void k_prep_all(const void* __restrict__ gs, const void* __restrict__ nsb,
                           ushort* __restrict__ B1, ushort* __restrict__ B2,
                           const void* W_msg, const void* W_nmsg,
                           const void* Wx_e, const void* Wh_e,
                           const void* Wx_n, const void* Wh_n,
                           const void* b_msg, const void* b_nmsg,
                           const void* bx_e, const void* bh_e,
                           const void* bx_n, const void* bh_n,
                           short* Wpq_e, short* Wpq_n,
                           short* Gxb_e, short* Ghb_e, short* Gxb_n, short* Ghb_n,
                           float* bm_e, float* bm_n,
                           float* bgx_e, float* bgh_e, float* bgx_n, float* bgh_n,
                           int E, const int* __restrict__ dflag)
{
    const int isf = *dflag;
    int b = blockIdx.x, t = threadIdx.x;
    const int ebi = (E * 64 + 255) / 256;

    if (b < ebi) {                      // link state init
        int i = b * 256 + t;
        if (i < E * 64) B1[i] = f2bs(ldv(gs, i, isf));
        return;
    }
    b -= ebi;
    if (b < ebi) {                      // node state init (padded to 64)
        int i = b * 256 + t;
        if (i < E * 64) {
            int e = i >> 6, c = i & 63;
            B2[i] = (c < DNODE) ? f2bs(ldv(nsb, (ll)e * DNODE + c, isf)) : 0;
        }
        return;
    }
    b -= ebi;
    if (b < 64) {                       // msg PQ weights: [8 kb][128 cols][8]
        const void* src = (b < 32) ? W_msg : W_nmsg;
        short* dst = (b < 32) ? Wpq_e : Wpq_n;
        int KH = (b < 32) ? 64 : DNODE;
        int i = (b & 31) * 256 + t;     // 0..8191
        int k = i >> 7, j = i & 127, half = j >> 6, c = j & 63;
        float v = 0.f;
        if (k < KH && c < KH) v = ldv(src, (ll)(half * KH + k) * KH + c, isf);
        dst[(k >> 3) * 1024 + j * 8 + (k & 7)] = (short)f2bs(v);
        return;
    }
    b -= 64;
    if (b < 192) {                      // GRU weights: [8 kb][192 cols][8]
        int w = b / 48, lb = b % 48;
        const void* src = (w == 0) ? Wx_e : (w == 1) ? Wh_e : (w == 2) ? Wx_n : Wh_n;
        short* dst = (w == 0) ? Gxb_e : (w == 1) ? Ghb_e : (w == 2) ? Gxb_n : Ghb_n;
        int D = (w < 2) ? 64 : DNODE;
        int i = lb * 256 + t;
        if (i >= 64 * 192) return;
        int k = i / 192, c = i % 192, g = c >> 6, d = c & 63;
        float v = 0.f;
        if (k < D && d < D) v = ldv(src, (ll)k * 3 * D + g * D + d, isf);
        dst[(k >> 3) * 1536 + c * 8 + (k & 7)] = (short)f2bs(v);
        return;
    }
    // biases (one block)
    for (int i = t; i < 896; i += 256) {
        if (i < 64)        bm_e[i] = ldv(b_msg, i, isf);
        else if (i < 128)  { int c = i - 64;  bm_n[c]  = (c < DNODE) ? ldv(b_nmsg, c, isf) : 0.f; }
        else if (i < 320)  { int c = i - 128; bgx_e[c] = ldv(bx_e, c, isf); }
        else if (i < 512)  { int c = i - 320; bgh_e[c] = ldv(bh_e, c, isf); }
        else if (i < 704)  { int c = i - 512; int g = c >> 6, d = c & 63;
                             bgx_n[c] = (d < DNODE) ? ldv(bx_n, (ll)g * DNODE + d, isf) : 0.f; }
        else               { int c = i - 704; int g = c >> 6, d = c & 63;
                             bgh_n[c] = (d < DNODE) ? ldv(bh_n, (ll)g * DNODE + d, isf) : 0.f; }
    }
}

// ---------------- counting sort of pairs by `second` ------------------------------
__global__ void k_hist(const int* __restrict__ second, int* __restrict__ cnt, int M)
{
    int m = blockIdx.x * 256 + threadIdx.x;
    if (m < M) atomicAdd(&cnt[second[m]], 1);
}
__global__ void k_scan_block(int* __restrict__ cnt, int* __restrict__ bsum, int E)
{
    __shared__ int s[256];
    int t = threadIdx.x, i = blockIdx.x * 256 + t;
    int v = (i < E) ? cnt[i] : 0;
    s[t] = v;
    __syncthreads();
    #pragma unroll
    for (int d = 1; d < 256; d <<= 1) {
        int xv = (t >= d) ? s[t - d] : 0;
        __syncthreads();
        s[t] += xv;
        __syncthreads();
    }
    if (i < E) cnt[i] = s[t] - v;
    if (t == 255) bsum[blockIdx.x] = s[255];
}
// parallel top-level scan (chunked 512-wide Hillis-Steele with carry)
__launch_bounds__(512)
__global__ void k_scan_top(const int* __restrict__ bsum, int* __restrict__ ebsum, int NB)
{
    __shared__ int s[512];
    const int t = threadIdx.x;
    int base = 0;
    for (int c0 = 0; c0 < NB; c0 += 512) {
        int b = c0 + t;
        int v = (b < NB) ? bsum[b] : 0;
        s[t] = v;
        __syncthreads();
        #pragma unroll
        for (int d = 1; d < 512; d <<= 1) {
            int xv = (t >= d) ? s[t - d] : 0;
            __syncthreads();
            s[t] += xv;
            __syncthreads();
        }
        if (b < NB) ebsum[b] = base + s[t] - v;
        int tot = s[511];
        __syncthreads();
        base += tot;
    }
}
__global__ void k_scan_add(int* __restrict__ cnt, const int* __restrict__ ebsum, int E)
{
    int i = blockIdx.x * 256 + threadIdx.x;
    if (i < E) cnt[i] += ebsum[blockIdx.x];
}
// scatter writes packed (first,second) int2 records
__global__ void k_scatter(const int* __restrict__ first, const int* __restrict__ second,
                          int* __restrict__ cnt, int2* __restrict__ prS, int M)
{
    int m = blockIdx.x * 256 + threadIdx.x;
    if (m < M) {
        int s = second[m];
        int pos = atomicAdd(&cnt[s], 1);
        prS[pos] = make_int2(first[m], s);
    }
}

// ---------------- counting sort of edges by graph id (atomic-free scatter) -------
__global__ void k_ghist2(const int* __restrict__ gid, int* __restrict__ gcnt,
                         int* __restrict__ blockHist, int E)
{
    __shared__ int h[NGRAPH];
    int t = threadIdx.x;
    h[t] = 0;
    __syncthreads();
    int i = blockIdx.x * 256 + t;
    if (i < E) atomicAdd(&h[gid[i]], 1);
    __syncthreads();
    blockHist[blockIdx.x * NGRAPH + t] = h[t];       // coalesced
    if (h[t]) atomicAdd(&gcnt[t], h[t]);
}
__global__ void k_gscan(const int* __restrict__ gcnt, int* __restrict__ gOff,
                        int* __restrict__ gpos)
{
    __shared__ int s[NGRAPH];
    int t = threadIdx.x;
    int v = gcnt[t];
    s[t] = v;
    __syncthreads();
    #pragma unroll
    for (int d = 1; d < 256; d <<= 1) {
        int xv = (t >= d) ? s[t - d] : 0;
        __syncthreads();
        s[t] += xv;
        __syncthreads();
    }
    int excl = s[t] - v;
    gOff[t] = excl;
    gpos[t] = excl;
    if (t == 255) gOff[256] = s[255];
}
__launch_bounds__(512)
__global__ void k_gbase2(const int* __restrict__ gOff, int* __restrict__ blockHist, int NB)
{
    __shared__ int s[512];
    const int g = blockIdx.x, t = threadIdx.x;
    int base = gOff[g];
    for (int c0 = 0; c0 < NB; c0 += 512) {
        int b = c0 + t;
        int v = (b < NB) ? blockHist[b * NGRAPH + g] : 0;
        s[t] = v;
        __syncthreads();
        #pragma unroll
        for (int d = 1; d < 512; d <<= 1) {
            int xv = (t >= d) ? s[t - d] : 0;
            __syncthreads();
            s[t] += xv;
            __syncthreads();
        }
        if (b < NB) blockHist[b * NGRAPH + g] = base + s[t] - v;
        int tot = s[511];
        __syncthreads();
        base += tot;
    }
}
__global__ void k_gscatter2(const int* __restrict__ gid, const int* __restrict__ blockHist,
                            int* __restrict__ eIdx, int E)
{
    __shared__ int h[NGRAPH];
    int t = threadIdx.x;
    h[t] = 0;
    __syncthreads();
    int i = blockIdx.x * 256 + t;
    if (i < E) {
        int g = gid[i];
        int r = atomicAdd(&h[g], 1);                 // LDS atomic: intra-block rank
        eIdx[blockHist[blockIdx.x * NGRAPH + g] + r] = i;
    }
}

// ---------------- dual-chain dense PQ GEMM: both chains in one launch ------------
__launch_bounds__(256)
__global__ void k_pq2(const ushort* __restrict__ B1, const ushort* __restrict__ B2,
                      const short* __restrict__ We, const short* __restrict__ Wn,
                      ushort* __restrict__ PQe, ushort* __restrict__ PQn,
                      int E, int eb)
{
    __shared__ __align__(16) short Ms16[64 * 136];   // 17,408 B relay
    int bb = blockIdx.x;
    const ushort* B; const short* Wb; ushort* PQ;
    if (bb < eb) { B = B1; Wb = We; PQ = PQe; }
    else { bb -= eb; B = B2; Wb = Wn; PQ = PQn; }

    const int t = threadIdx.x;
    const int e0 = bb * 64;
    const int lane = t & 63, wv = t >> 6, quad = lane >> 4, l16 = lane & 15;
    const int em = wv * 16;

    int er = e0 + em + l16; if (er >= E) er = E - 1;

    float4v acc[8];
    #pragma unroll
    for (int i = 0; i < 8; ++i) acc[i] = (float4v){0.f, 0.f, 0.f, 0.f};

    #pragma unroll
    for (int c = 0; c < 2; ++c) {
        int kb = c * 4 + quad;
        short8v a = *(const short8v*)&B[(ll)er * 64 + kb * 8];
        #pragma unroll
        for (int tn = 0; tn < 8; ++tn) {
            short8v bw = *(const short8v*)&Wb[(kb * 128 + tn * 16 + l16) * 8];
            acc[tn] = __builtin_amdgcn_mfma_f32_16x16x32_bf16(a, bw, acc[tn], 0, 0, 0);
        }
    }

    // relay acc -> bf16 LDS -> coalesced PQ store
    #pragma unroll
    for (int tn = 0; tn < 8; ++tn)
        #pragma unroll
        for (int r = 0; r < 4; ++r)
            Ms16[(em + quad * 4 + r) * 136 + tn * 16 + l16] = (short)f2bs(acc[tn][r]);
    __syncthreads();
    #pragma unroll
    for (int r = 0; r < 4; ++r) {
        int id = t + r * 256;
        int row = id >> 4, q = id & 15;
        if (e0 + row < E)
            *(uint4*)&PQ[(ll)(e0 + row) * 128 + q * 8] = *(uint4*)&Ms16[row * 136 + q * 8];
    }
}

// ---------------- dual-chain scatter-agg: one wave per 64-pair span --------------
// Round-14: prefetch ring deepened 4 -> 8 packs (16 pairs lookahead, 16
// outstanding loads per wave) to double memory-level parallelism; the kernel
// is latency-bound (45 us vs ~12 us BW floor). Scalar-mask control, single-
// shfl refill, half-wave pair packing, int2-packed index records unchanged.
__launch_bounds__(256)
__global__ void k_scat2(const ushort* __restrict__ PQe, const ushort* __restrict__ PQn,
                        const int2* __restrict__ prS,
                        const float* __restrict__ bme, const float* __restrict__ bmn,
                        ushort* __restrict__ agge, ushort* __restrict__ aggn,
                        ushort* __restrict__ bVe, ushort* __restrict__ bVn,
                        int* __restrict__ bDe, int* __restrict__ bDn,
                        int M, int scb)
{
    int bb = blockIdx.x;
    const ushort* PQ; const float* bm; ushort* aggb; ushort* bndVal; int* bndDst;
    if (bb < scb) { PQ = PQe; bm = bme; aggb = agge; bndVal = bVe; bndDst = bDe; }
    else { bb -= scb; PQ = PQn; bm = bmn; aggb = aggn; bndVal = bVn; bndDst = bDn; }

    const int lane = threadIdx.x & 63, wv = threadIdx.x >> 6;
    const int hl = lane & 31;
    const bool isUp = lane >= 32;
    const int sp = bb * 4 + wv;
    const int m0 = sp * 64;
    const float bba = bm[2 * hl], bbb = bm[2 * hl + 1];
    const unsigned* PQu = (const unsigned*)PQ;   // row r: P dwords [r*64+hl], Q [r*64+32+hl]
    unsigned* aggu = (unsigned*)aggb;
    unsigned* bVu  = (unsigned*)bndVal;

    int mm = m0 + lane;
    int2 pr = (mm < M) ? prS[mm] : make_int2(0, -1);
    int fiv = pr.x, sev = pr.y;

    int cur = __builtin_amdgcn_readlane(sev, 0);
    if (cur < 0) {
        if (lane == 0) { bndDst[2 * sp] = -1; bndDst[2 * sp + 1] = -1; }
        return;
    }

    // wave-uniform scalar masks (computed once per span)
    unsigned long long vmask = __ballot(sev >= 0);
    int prevv = __shfl_up(sev, 1);
    unsigned long long bmask = __ballot(lane > 0 && sev != prevv);

    float sa = 0.f, sb = 0.f;
    bool headDone = false;
    auto FLUSH = [&](int nxt) {
        float ta = sa + __shfl_xor(sa, 32);
        float tb = sb + __shfl_xor(sb, 32);
        unsigned w = (unsigned)f2bs(ta) | ((unsigned)f2bs(tb) << 16);
        if (!headDone) {
            if (!isUp) bVu[(ll)(2 * sp) * 32 + hl] = w;
            if (lane == 0) bndDst[2 * sp] = cur;
            headDone = true;
        } else {
            if (!isUp) aggu[(ll)cur * 32 + hl] = w;
        }
        sa = 0.f; sb = 0.f; cur = nxt;
    };

    unsigned pu[8], qu[8];
    #pragma unroll
    for (int u = 0; u < 8; ++u) {       // prologue: packs 0..7 (pairs 0..15)
        int idx = 2 * u + (isUp ? 1 : 0);
        int fr = __shfl(fiv, idx);
        int sr = max(__shfl(sev, idx), 0);
        pu[u] = PQu[(size_t)(unsigned)fr * 64 + hl];
        qu[u] = PQu[(size_t)(unsigned)sr * 64 + 32 + hl];
    }

    for (int k0 = 0; k0 < 32; k0 += 8) {
        #pragma unroll
        for (int u = 0; u < 8; ++u) {
            int k = k0 + u;
            unsigned pw = pu[u], qw = qu[u];
            int k8 = k + 8;
            if (k8 < 32) {              // refill pack k+8 into slot u
                int idx = 2 * k8 + (isUp ? 1 : 0);
                int fr = __shfl(fiv, idx);
                int sr = max(__shfl(sev, idx), 0);
                pu[u] = PQu[(size_t)(unsigned)fr * 64 + hl];
                qu[u] = PQu[(size_t)(unsigned)sr * 64 + 32 + hl];
            }
            float pa = bs2f((ushort)(pw & 0xffffu)), pb = bs2f((ushort)(pw >> 16));
            float qa = bs2f((ushort)(qw & 0xffffu)), qb = bs2f((ushort)(qw >> 16));
            float ca = selu_f(pa + qa + bba);
            float cb = selu_f(pb + qb + bbb);
            // pair 2k (owned by lower half)
            if ((bmask >> (2 * k)) & 1ull)
                FLUSH(__builtin_amdgcn_readlane(sev, 2 * k));
            if ((vmask >> (2 * k)) & 1ull) {
                if (!isUp) { sa += ca; sb += cb; }
            }
            // pair 2k+1 (owned by upper half)
            if ((bmask >> (2 * k + 1)) & 1ull)
                FLUSH(__builtin_amdgcn_readlane(sev, 2 * k + 1));
            if ((vmask >> (2 * k + 1)) & 1ull) {
                if (isUp) { sa += ca; sb += cb; }
            }
        }
    }
    // final record
    {
        float ta = sa + __shfl_xor(sa, 32);
        float tb = sb + __shfl_xor(sb, 32);
        unsigned w = (unsigned)f2bs(ta) | ((unsigned)f2bs(tb) << 16);
        if (!headDone) {
            if (!isUp) bVu[(ll)(2 * sp) * 32 + hl] = w;
            if (lane == 0) { bndDst[2 * sp] = cur; bndDst[2 * sp + 1] = -1; }
        } else {
            if (!isUp) bVu[(ll)(2 * sp + 1) * 32 + hl] = w;
            if (lane == 0) bndDst[2 * sp + 1] = cur;
        }
    }
}

// ---------------- dual-chain boundary fixup --------------------------------------
__global__ void k_fix2(const int* __restrict__ bDe, const int* __restrict__ bDn,
                       const ushort* __restrict__ bVe, const ushort* __restrict__ bVn,
                       ushort* __restrict__ agge, ushort* __restrict__ aggn,
                       int NR, int fixb)
{
    int bb = blockIdx.x;
    const int* bndDst; const ushort* bndVal; ushort* aggb;
    if (bb < fixb) { bndDst = bDe; bndVal = bVe; aggb = agge; }
    else { bb -= fixb; bndDst = bDn; bndVal = bVn; aggb = aggn; }

    int idx = (bb * 256 + threadIdx.x) >> 6;
    int lane = threadIdx.x & 63;
    if (idx >= NR) return;
    int dst = bndDst[idx];
    if (dst < 0) return;
    int pprev = idx - 1;
    while (pprev >= 0 && bndDst[pprev] < 0) --pprev;
    if (pprev >= 0 && bndDst[pprev] == dst) return;    // not chain head
    float s = 0.f;
    for (int r = idx; r < NR; ++r) {
        int d = bndDst[r];
        if (d == dst) s += bs2f(bndVal[(ll)r * 64 + lane]);
        else if (d >= 0) break;
    }
    aggb[(ll)dst * 64 + lane] = f2bs(s);
}

// ---------------- dual-chain GRU: joint z/r accumulators, LDS-relayed ho ---------
__launch_bounds__(256)
__global__ void k_gru2(const ushort* __restrict__ agge, const ushort* __restrict__ aggn,
                       ushort* __restrict__ B1, ushort* __restrict__ B2,
                       const short* __restrict__ Gxe, const short* __restrict__ Gxn,
                       const short* __restrict__ Ghe, const short* __restrict__ Ghn,
                       const float* __restrict__ bxe, const float* __restrict__ bxn,
                       const float* __restrict__ bhe, const float* __restrict__ bhn,
                       int E, int eb)
{
    __shared__ __align__(16) short Hs[64 * 64];      // 8 KB swizzled h relay
    int bb = blockIdx.x;
    const ushort* xb; ushort* hb; const short* Gxb; const short* Ghb;
    const float* bgx; const float* bgh;
    if (bb < eb) { xb = agge; hb = B1; Gxb = Gxe; Ghb = Ghe; bgx = bxe; bgh = bhe; }
    else { bb -= eb; xb = aggn; hb = B2; Gxb = Gxn; Ghb = Ghn; bgx = bxn; bgh = bhn; }

    const int t = threadIdx.x;
    const int e0 = bb * 64;
    const int lane = t & 63, wv = t >> 6, quad = lane >> 4, l16 = lane & 15;
    const int em = wv * 16;
    int er = e0 + em + l16; if (er >= E) er = E - 1;
    const int hrow = em + l16;                       // block-local row this lane loads

    float4v zr[8], xh[4], hh[4];
    #pragma unroll
    for (int i = 0; i < 8; ++i) zr[i] = (float4v){0.f, 0.f, 0.f, 0.f};
    #pragma unroll
    for (int i = 0; i < 4; ++i) { xh[i] = (float4v){0.f,0.f,0.f,0.f}; hh[i] = (float4v){0.f,0.f,0.f,0.f}; }

    #pragma unroll
    for (int c = 0; c < 2; ++c) {
        int kb = c * 4 + quad;
        short8v a_x = *(const short8v*)&xb[(ll)er * 64 + kb * 8];
        short8v a_h = *(const short8v*)&hb[(ll)er * 64 + kb * 8];
        // stage h fragment into swizzled LDS (intra-wave rows only)
        *(short8v*)&Hs[hrow * 64 + ((kb ^ (hrow & 7)) << 3)] = a_h;
        #pragma unroll
        for (int tn = 0; tn < 8; ++tn) {    // z,r gates: x and h into one acc
            short8v b_x = *(const short8v*)&Gxb[(kb * 192 + tn * 16 + l16) * 8];
            zr[tn] = __builtin_amdgcn_mfma_f32_16x16x32_bf16(a_x, b_x, zr[tn], 0, 0, 0);
            short8v b_h = *(const short8v*)&Ghb[(kb * 192 + tn * 16 + l16) * 8];
            zr[tn] = __builtin_amdgcn_mfma_f32_16x16x32_bf16(a_h, b_h, zr[tn], 0, 0, 0);
        }
        #pragma unroll
        for (int tn = 0; tn < 4; ++tn) {    // hh gate: keep x and h separate
            short8v b_x = *(const short8v*)&Gxb[(kb * 192 + (8 + tn) * 16 + l16) * 8];
            xh[tn] = __builtin_amdgcn_mfma_f32_16x16x32_bf16(a_x, b_x, xh[tn], 0, 0, 0);
            short8v b_h = *(const short8v*)&Ghb[(kb * 192 + (8 + tn) * 16 + l16) * 8];
            hh[tn] = __builtin_amdgcn_mfma_f32_16x16x32_bf16(a_h, b_h, hh[tn], 0, 0, 0);
        }
    }

    // hoisted biases
    float bz[4], br_[4], bxh[4], bhh[4];
    #pragma unroll
    for (int j = 0; j < 4; ++j) {
        int d = j * 16 + l16;
        bz[j]  = bgx[d] + bgh[d];
        br_[j] = bgx[64 + d] + bgh[64 + d];
        bxh[j] = bgx[128 + d];
        bhh[j] = bgh[128 + d];
    }

    #pragma unroll
    for (int r = 0; r < 4; ++r) {
        int rowl = em + quad * 4 + r;       // block-local (within this wave's 16 rows)
        int e = e0 + rowl;
        if (e >= E) continue;
        #pragma unroll
        for (int j = 0; j < 4; ++j) {
            int d = j * 16 + l16;
            float z  = fsigmoid(zr[j][r] + bz[j]);
            float rr = fsigmoid(zr[4 + j][r] + br_[j]);
            float cc = ftanh(xh[j][r] + bxh[j] + rr * (hh[j][r] + bhh[j]));
            float ho = bs2f((ushort)Hs[rowl * 64 + ((((d >> 3) ^ (rowl & 7)) << 3) | (d & 7))]);
            hb[(ll)e * 64 + d] = f2bs(z * ho + (1.f - z) * cc);
        }
    }
}

// ---------------- span-parallel pooling over gid-sorted edges --------------------
__launch_bounds__(256)
__global__ void k_pool2(const ushort* __restrict__ lsb, const ushort* __restrict__ nsb,
                        const int* __restrict__ eIdx, const int* __restrict__ gid,
                        float* __restrict__ pooled, int E)
{
    const int t = threadIdx.x, lane = t & 63, wv = t >> 6;
    const int span = blockIdx.x * 2 + (wv >> 1);
    const int colhalf = wv & 1;
    const int s0 = span * 64;
    if (s0 >= E) return;

    int idx = s0 + lane;
    int ei = (idx < E) ? eIdx[idx] : 0;
    int gv = (idx < E) ? gid[ei] : -1;
    const ushort* src = colhalf ? nsb : lsb;   // node pad cols are exact zeros
    const int cb = colhalf ? 64 : 0;

    float pv[4];
    #pragma unroll
    for (int u = 0; u < 4; ++u) {
        int e = __shfl(ei, u);
        pv[u] = bs2f(src[(ll)e * 64 + lane]);
    }

    int curg = __shfl(gv, 0);                  // lane 0 always valid (s0 < E)
    float acc = 0.f;
    for (int i0 = 0; i0 < 64; i0 += 4) {
        #pragma unroll
        for (int u = 0; u < 4; ++u) {
            int i = i0 + u;
            int g = __shfl(gv, i);
            float v = pv[u];
            int i4 = i + 4;
            if (i4 < 64) {                     // prefetch ring refill
                int e = __shfl(ei, i4);
                pv[u] = bs2f(src[(ll)e * 64 + lane]);
            }
            if (g >= 0) {
                if (g != curg) {
                    atomicAdd(&pooled[curg * 128 + cb + lane], acc);
                    curg = g; acc = 0.f;
                }
                acc += v;
            }
        }
    }
    atomicAdd(&pooled[curg * 128 + cb + lane], acc);
}

// ---------------- fused per-graph MLP: typed body, 4-way k-split, 16 waves -------
template <typename T>
__device__ __forceinline__ void mlp_body(const float* __restrict__ pooled,
                                         const T* __restrict__ W1, const T* __restrict__ b1,
                                         const T* __restrict__ W2, const T* __restrict__ b2,
                                         const T* __restrict__ W3, const T* __restrict__ b3,
                                         void* __restrict__ out, int isf)
{
    __shared__ float pooledS[128];
    __shared__ float h1s[256];
    __shared__ float ps[4][256];
    __shared__ float red[256];
    const int g = blockIdx.x, t = threadIdx.x;
    const int j = t & 255, s = t >> 8;          // 1024 threads: 4 k-splits x 256 cols

    if (t < 128) pooledS[t] = pooled[g * 128 + t];
    __syncthreads();

    {   // layer 1: K = 123, split 4 x 31
        int k0 = s * 31, k1 = min(64 + DNODE, k0 + 31);
        float a = 0.f;
        #pragma unroll 4
        for (int k = k0; k < k1; ++k)
            a = fmaf(pooledS[k], ldT<T>(W1, (ll)k * 256 + j), a);
        ps[s][j] = a;
    }
    __syncthreads();
    if (t < 256) {
        float a1 = ldT<T>(b1, t) + ps[0][t] + ps[1][t] + ps[2][t] + ps[3][t];
        h1s[t] = selu_f(a1);
    }
    __syncthreads();

    {   // layer 2: K = 256, split 4 x 64
        int k0 = s * 64;
        float a = 0.f;
        #pragma unroll 8
        for (int k = k0; k < k0 + 64; ++k)
            a = fmaf(h1s[k], ldT<T>(W2, (ll)k * 256 + j), a);
        ps[s][j] = a;
    }
    __syncthreads();
    if (t < 256) {
        float a2 = ldT<T>(b2, t) + ps[0][t] + ps[1][t] + ps[2][t] + ps[3][t];
        red[t] = selu_f(a2) * ldT<T>(W3, t);
    }
    __syncthreads();
    for (int sdt = 128; sdt > 0; sdt >>= 1) {
        if (t < sdt) red[t] += red[t + sdt];
        __syncthreads();
    }
    if (t == 0) {
        float o = red[0] + ldT<T>(b3, 0);
        if (isf) ((float*)out)[g] = o;
        else     ((bf16*)out)[g] = __float2bfloat16(o);
    }
}
__launch_bounds__(1024)
__global__ void k_mlpall(const float* __restrict__ pooled,
                         const void* __restrict__ W1, const void* __restrict__ b1,
                         const void* __restrict__ W2, const void* __restrict__ b2,
                         const void* __restrict__ W3, const void* __restrict__ b3,
                         void* __restrict__ out, const int* __restrict__ dflag)
{
    const int isf = *dflag;                     // hoisted dtype branch
    if (isf) mlp_body<float>(pooled, (const float*)W1, (const float*)b1,
                             (const float*)W2, (const float*)b2,
                             (const float*)W3, (const float*)b3, out, 1);
    else     mlp_body<bf16> (pooled, (const bf16*)W1, (const bf16*)b1,
                             (const bf16*)W2, (const bf16*)b2,
                             (const bf16*)W3, (const bf16*)b3, out, 0);
}

extern "C" void kernel_launch(void* const* d_in, const int* in_sizes, int n_in,
                              void* d_out, int out_size, void* d_ws, size_t ws_size,
                              hipStream_t stream)
{
    const void* graph_state = d_in[0];
    const void* node_state  = d_in[1];
    const int*  first   = (const int*)d_in[2];
    const int*  second  = (const int*)d_in[3];
    const int*  gid     = (const int*)d_in[4];
    const void* W_msg  = d_in[6];
    const void* b_msg  = d_in[7];
    const void* Wx_e   = d_in[8];
    const void* Wh_e   = d_in[9];
    const void* bx_e   = d_in[10];
    const void* bh_e   = d_in[11];
    const void* W_nmsg = d_in[12];
    const void* b_nmsg = d_in[13];
    const void* Wx_n   = d_in[14];
    const void* Wh_n   = d_in[15];
    const void* bx_n   = d_in[16];
    const void* bh_n   = d_in[17];
    const void* W1 = d_in[18];
    const void* b1 = d_in[19];
    const void* W2 = d_in[20];
    const void* b2 = d_in[21];
    const void* W3 = d_in[22];
    const void* b3 = d_in[23];

    const int E = in_sizes[0] / 64;      // 100000
    const int M = in_sizes[2];           // 300000
    const int eb   = (E + 63) / 64;      // per-chain k_pq2 / k_gru2 blocks
    const int nsp  = (M + 63) / 64;      // 64-pair spans
    const int scb  = (nsp + 3) / 4;      // per-chain k_scat2 blocks (4 waves each)
    const int NR   = 2 * scb * 4;        // boundary records per chain (covers tail)
    const int fixb = (NR * 64 + 255) / 256;
    const int psp  = (E + 63) / 64;      // pooling spans
    const int plb  = (psp + 1) / 2;      // k_pool2 blocks (2 spans each)

    // ---- workspace layout (~107 MB) ----
    ushort* B1    = (ushort*)d_ws;                  // bf16 link state [E*64]
    ushort* B2    = B1 + (size_t)E * 64;            // bf16 node state [E*64]
    ushort* agge  = B2 + (size_t)E * 64;            // bf16 link agg [E*64]
    ushort* aggn  = agge + (size_t)E * 64;          // bf16 node agg [E*64]
    ushort* PQe   = aggn + (size_t)E * 64;          // bf16 [E*128]
    ushort* PQn   = PQe + (size_t)E * 128;          // bf16 [E*128]
    int2*   prS   = (int2*)(PQn + (size_t)E * 128); // packed (first,second) [M]
    ushort* bVe   = (ushort*)(prS + M);             // [NR*64]
    ushort* bVn   = bVe + (size_t)NR * 64;          // [NR*64]
    int*    bDe   = (int*)(bVn + (size_t)NR * 64);
    int*    bDn   = bDe + NR;
    short*  sb    = (short*)(bDn + NR);
    size_t so = 0;
    short* Wpq_e = sb + so; so += 8192;
    short* Wpq_n = sb + so; so += 8192;
    short* Gxb_e = sb + so; so += 12288;
    short* Ghb_e = sb + so; so += 12288;
    short* Gxb_n = sb + so; so += 12288;
    short* Ghb_n = sb + so; so += 12288;
    float* fb = (float*)(sb + so);
    size_t fo = 0;
    float* bm_e  = fb + fo; fo += 64;
    float* bm_n  = fb + fo; fo += 64;
    float* bgx_e = fb + fo; fo += 192;
    float* bgh_e = fb + fo; fo += 192;
    float* bgx_n = fb + fo; fo += 192;
    float* bgh_n = fb + fo; fo += 192;
    int* dflag = (int*)(fb + fo);
    // gid-sort scratch (static indices)
    int* gcnt = dflag + 1;                 // [256]
    int* gpos = gcnt + 256;                // [256]
    int* gOff = gcnt + 512;                // [257]
    int* eIdx = gcnt + 769;                // [E]
    // overlays: sort scratch in agge (free before MP loop); blockHist in PQe
    // (free before MP loop); pooled in PQe (free after MP loop)
    int* cnt   = (int*)agge;
    int* bsum  = cnt + E;
    int* ebsum = bsum + 512;
    int* blockHist = (int*)PQe;            // [NB_E * NGRAPH]
    float* pooled = (float*)PQe;           // [NGRAPH*128] fp32 (post-MP)

    // ---- dtype detect (+ zero gid-sort counters) + fused init/prep ----
    k_detect<<<1, 512, 0, stream>>>((const ushort*)graph_state, dflag, gcnt);
    const int ebi = (E * 64 + 255) / 256;
    k_prep_all<<<2 * ebi + 64 + 192 + 1, 256, 0, stream>>>(
        graph_state, node_state, B1, B2,
        W_msg, W_nmsg, Wx_e, Wh_e, Wx_n, Wh_n,
        b_msg, b_nmsg, bx_e, bh_e, bx_n, bh_n,
        Wpq_e, Wpq_n, Gxb_e, Ghb_e, Gxb_n, Ghb_n,
        bm_e, bm_n, bgx_e, bgh_e, bgx_n, bgh_n, E, dflag);

    // ---- counting sort by `second` -> prS (scratch overlays agge) ----
    const int NB = (E + 255) / 256;
    hipMemsetAsync(cnt, 0, (size_t)E * sizeof(int), stream);
    k_hist<<<(M + 255) / 256, 256, 0, stream>>>(second, cnt, M);
    k_scan_block<<<NB, 256, 0, stream>>>(cnt, bsum, E);
    k_scan_top<<<1, 512, 0, stream>>>(bsum, ebsum, NB);
    k_scan_add<<<NB, 256, 0, stream>>>(cnt, ebsum, E);
    k_scatter<<<(M + 255) / 256, 256, 0, stream>>>(first, second, cnt, prS, M);

    // ---- one-time agg zeroing (agge|aggn contiguous; sort scratch now dead).
    hipMemsetAsync(agge, 0, (size_t)2 * E * 64 * sizeof(ushort), stream);

    // ---- counting sort of edges by gid -> eIdx (atomic-free scatter) ----
    k_ghist2<<<NB, 256, 0, stream>>>(gid, gcnt, blockHist, E);
    k_gscan<<<1, 256, 0, stream>>>(gcnt, gOff, gpos);
    k_gbase2<<<NGRAPH, 512, 0, stream>>>(gOff, blockHist, NB);
    k_gscatter2<<<NB, 256, 0, stream>>>(gid, blockHist, eIdx, E);

    // ---- message passing: link+node chains merged per dispatch (independent) ----
    for (int it = 0; it < 4; ++it) {
        k_pq2  <<<2 * eb,   256, 0, stream>>>(B1, B2, Wpq_e, Wpq_n, PQe, PQn, E, eb);
        k_scat2<<<2 * scb,  256, 0, stream>>>(PQe, PQn, prS, bm_e, bm_n,
                                              agge, aggn, bVe, bVn, bDe, bDn, M, scb);
        k_fix2 <<<2 * fixb, 256, 0, stream>>>(bDe, bDn, bVe, bVn, agge, aggn, NR, fixb);
        k_gru2 <<<2 * eb,   256, 0, stream>>>(agge, aggn, B1, B2,
                                              Gxb_e, Gxb_n, Ghb_e, Ghb_n,
                                              bgx_e, bgx_n, bgh_e, bgh_n, E, eb);
    }

    // ---- readout: span-parallel pool + fused per-graph MLP ----
    hipMemsetAsync(pooled, 0, (size_t)NGRAPH * 128 * sizeof(float), stream);
    k_pool2<<<plb, 256, 0, stream>>>(B1, B2, eIdx, gid, pooled, E);
    k_mlpall<<<NGRAPH, 1024, 0, stream>>>(pooled, W1, b1, W2, b2, W3, b3, d_out, dflag);
}

// Round 15
// 604.010 us; speedup vs baseline: 1.0712x; 1.0712x over previous
//
#include <hip/hip_runtime.h>
#include <hip/hip_bf16.h>

#define DNODE 59
#define NGRAPH 256
typedef __hip_bfloat16 bf16;
typedef long long ll;
typedef unsigned short ushort;
typedef short short8v __attribute__((ext_vector_type(8)));
typedef float float4v __attribute__((ext_vector_type(4)));

__device__ __forceinline__ float b2f(bf16 x) { return __bfloat162float(x); }
__device__ __forceinline__ float bs2f(ushort u) {
    return __uint_as_float(((unsigned int)u) << 16);
}
__device__ __forceinline__ float ldv(const void* p, ll i, int isf) {
    return isf ? ((const float*)p)[i] : b2f(((const bf16*)p)[i]);
}
__device__ __forceinline__ ushort f2bs(float x) {   // RNE
    unsigned int u = __float_as_uint(x);
    u += 0x7fffu + ((u >> 16) & 1u);
    return (ushort)(u >> 16);
}
__device__ __forceinline__ float frcp(float x) { return __builtin_amdgcn_rcpf(x); }
__device__ __forceinline__ float selu_f(float x) {
    const float scale = 1.0507009873554805f;
    const float alpha = 1.6732632423543772f;
    return x > 0.f ? scale * x : scale * alpha * (__expf(x) - 1.f);
}
__device__ __forceinline__ float fsigmoid(float x) { return frcp(1.f + __expf(-x)); }
__device__ __forceinline__ float ftanh(float x) {
    float t = __expf(-2.f * fabsf(x));
    return copysignf((1.f - t) * frcp(1.f + t), x);
}

// typed load (branch hoisted OUT of loops -> compiler can pipeline)
template <typename T>
__device__ __forceinline__ float ldT(const T* p, ll i);
template <> __device__ __forceinline__ float ldT<float>(const float* p, ll i) { return p[i]; }
template <> __device__ __forceinline__ float ldT<bf16>(const bf16* p, ll i)  { return b2f(p[i]); }

// ---------------- dtype detector (parallel) + gid-sort scratch zeroing -----------
__global__ void k_detect(const ushort* __restrict__ gsu, int* __restrict__ flag,
                         int* __restrict__ gcnt)
{
    __shared__ int wilds;
    int t = threadIdx.x;
    if (t == 0) wilds = 0;
    if (t < 512) gcnt[t] = 0;          // gcnt[256] + gpos[256]
    __syncthreads();
    int e = (gsu[t] >> 7) & 0xFF;      // 512 threads, one sample each
    if (e >= 0x8F) atomicAdd(&wilds, 1);
    __syncthreads();
    if (t == 0) *flag = (wilds >= 20) ? 1 : 0;
}

// ---------------- fused init + weight prep (one launch) --------------------------
__global__ void k_prep_all(const void* __restrict__ gs, const void* __restrict__ nsb,
                           ushort* __restrict__ B1, ushort* __restrict__ B2,
                           const void* W_msg, const void* W_nmsg,
                           const void* Wx_e, const void* Wh_e,
                           const void* Wx_n, const void* Wh_n,
                           const void* b_msg, const void* b_nmsg,
                           const void* bx_e, const void* bh_e,
                           const void* bx_n, const void* bh_n,
                           short* Wpq_e, short* Wpq_n,
                           short* Gxb_e, short* Ghb_e, short* Gxb_n, short* Ghb_n,
                           float* bm_e, float* bm_n,
                           float* bgx_e, float* bgh_e, float* bgx_n, float* bgh_n,
                           int E, const int* __restrict__ dflag)
{
    const int isf = *dflag;
    int b = blockIdx.x, t = threadIdx.x;
    const int ebi = (E * 64 + 255) / 256;

    if (b < ebi) {                      // link state init
        int i = b * 256 + t;
        if (i < E * 64) B1[i] = f2bs(ldv(gs, i, isf));
        return;
    }
    b -= ebi;
    if (b < ebi) {                      // node state init (padded to 64)
        int i = b * 256 + t;
        if (i < E * 64) {
            int e = i >> 6, c = i & 63;
            B2[i] = (c < DNODE) ? f2bs(ldv(nsb, (ll)e * DNODE + c, isf)) : 0;
        }
        return;
    }
    b -= ebi;
    if (b < 64) {                       // msg PQ weights: [8 kb][128 cols][8]
        const void* src = (b < 32) ? W_msg : W_nmsg;
        short* dst = (b < 32) ? Wpq_e : Wpq_n;
        int KH = (b < 32) ? 64 : DNODE;
        int i = (b & 31) * 256 + t;     // 0..8191
        int k = i >> 7, j = i & 127, half = j >> 6, c = j & 63;
        float v = 0.f;
        if (k < KH && c < KH) v = ldv(src, (ll)(half * KH + k) * KH + c, isf);
        dst[(k >> 3) * 1024 + j * 8 + (k & 7)] = (short)f2bs(v);
        return;
    }
    b -= 64;
    if (b < 192) {                      // GRU weights: [8 kb][192 cols][8]
        int w = b / 48, lb = b % 48;
        const void* src = (w == 0) ? Wx_e : (w == 1) ? Wh_e : (w == 2) ? Wx_n : Wh_n;
        short* dst = (w == 0) ? Gxb_e : (w == 1) ? Ghb_e : (w == 2) ? Gxb_n : Ghb_n;
        int D = (w < 2) ? 64 : DNODE;
        int i = lb * 256 + t;
        if (i >= 64 * 192) return;
        int k = i / 192, c = i % 192, g = c >> 6, d = c & 63;
        float v = 0.f;
        if (k < D && d < D) v = ldv(src, (ll)k * 3 * D + g * D + d, isf);
        dst[(k >> 3) * 1536 + c * 8 + (k & 7)] = (short)f2bs(v);
        return;
    }
    // biases (one block)
    for (int i = t; i < 896; i += 256) {
        if (i < 64)        bm_e[i] = ldv(b_msg, i, isf);
        else if (i < 128)  { int c = i - 64;  bm_n[c]  = (c < DNODE) ? ldv(b_nmsg, c, isf) : 0.f; }
        else if (i < 320)  { int c = i - 128; bgx_e[c] = ldv(bx_e, c, isf); }
        else if (i < 512)  { int c = i - 320; bgh_e[c] = ldv(bh_e, c, isf); }
        else if (i < 704)  { int c = i - 512; int g = c >> 6, d = c & 63;
                             bgx_n[c] = (d < DNODE) ? ldv(bx_n, (ll)g * DNODE + d, isf) : 0.f; }
        else               { int c = i - 704; int g = c >> 6, d = c & 63;
                             bgh_n[c] = (d < DNODE) ? ldv(bh_n, (ll)g * DNODE + d, isf) : 0.f; }
    }
}

// ---------------- counting sort of pairs by `second` ------------------------------
__global__ void k_hist(const int* __restrict__ second, int* __restrict__ cnt, int M)
{
    int m = blockIdx.x * 256 + threadIdx.x;
    if (m < M) atomicAdd(&cnt[second[m]], 1);
}
__global__ void k_scan_block(int* __restrict__ cnt, int* __restrict__ bsum, int E)
{
    __shared__ int s[256];
    int t = threadIdx.x, i = blockIdx.x * 256 + t;
    int v = (i < E) ? cnt[i] : 0;
    s[t] = v;
    __syncthreads();
    #pragma unroll
    for (int d = 1; d < 256; d <<= 1) {
        int xv = (t >= d) ? s[t - d] : 0;
        __syncthreads();
        s[t] += xv;
        __syncthreads();
    }
    if (i < E) cnt[i] = s[t] - v;
    if (t == 255) bsum[blockIdx.x] = s[255];
}
// parallel top-level scan (chunked 512-wide Hillis-Steele with carry)
__launch_bounds__(512)
__global__ void k_scan_top(const int* __restrict__ bsum, int* __restrict__ ebsum, int NB)
{
    __shared__ int s[512];
    const int t = threadIdx.x;
    int base = 0;
    for (int c0 = 0; c0 < NB; c0 += 512) {
        int b = c0 + t;
        int v = (b < NB) ? bsum[b] : 0;
        s[t] = v;
        __syncthreads();
        #pragma unroll
        for (int d = 1; d < 512; d <<= 1) {
            int xv = (t >= d) ? s[t - d] : 0;
            __syncthreads();
            s[t] += xv;
            __syncthreads();
        }
        if (b < NB) ebsum[b] = base + s[t] - v;
        int tot = s[511];
        __syncthreads();
        base += tot;
    }
}
__global__ void k_scan_add(int* __restrict__ cnt, const int* __restrict__ ebsum, int E)
{
    int i = blockIdx.x * 256 + threadIdx.x;
    if (i < E) cnt[i] += ebsum[blockIdx.x];
}
// scatter writes packed (first,second) int2 records
__global__ void k_scatter(const int* __restrict__ first, const int* __restrict__ second,
                          int* __restrict__ cnt, int2* __restrict__ prS, int M)
{
    int m = blockIdx.x * 256 + threadIdx.x;
    if (m < M) {
        int s = second[m];
        int pos = atomicAdd(&cnt[s], 1);
        prS[pos] = make_int2(first[m], s);
    }
}

// ---------------- counting sort of edges by graph id (atomic-free scatter) -------
__global__ void k_ghist2(const int* __restrict__ gid, int* __restrict__ gcnt,
                         int* __restrict__ blockHist, int E)
{
    __shared__ int h[NGRAPH];
    int t = threadIdx.x;
    h[t] = 0;
    __syncthreads();
    int i = blockIdx.x * 256 + t;
    if (i < E) atomicAdd(&h[gid[i]], 1);
    __syncthreads();
    blockHist[blockIdx.x * NGRAPH + t] = h[t];       // coalesced
    if (h[t]) atomicAdd(&gcnt[t], h[t]);
}
__global__ void k_gscan(const int* __restrict__ gcnt, int* __restrict__ gOff,
                        int* __restrict__ gpos)
{
    __shared__ int s[NGRAPH];
    int t = threadIdx.x;
    int v = gcnt[t];
    s[t] = v;
    __syncthreads();
    #pragma unroll
    for (int d = 1; d < 256; d <<= 1) {
        int xv = (t >= d) ? s[t - d] : 0;
        __syncthreads();
        s[t] += xv;
        __syncthreads();
    }
    int excl = s[t] - v;
    gOff[t] = excl;
    gpos[t] = excl;
    if (t == 255) gOff[256] = s[255];
}
__launch_bounds__(512)
__global__ void k_gbase2(const int* __restrict__ gOff, int* __restrict__ blockHist, int NB)
{
    __shared__ int s[512];
    const int g = blockIdx.x, t = threadIdx.x;
    int base = gOff[g];
    for (int c0 = 0; c0 < NB; c0 += 512) {
        int b = c0 + t;
        int v = (b < NB) ? blockHist[b * NGRAPH + g] : 0;
        s[t] = v;
        __syncthreads();
        #pragma unroll
        for (int d = 1; d < 512; d <<= 1) {
            int xv = (t >= d) ? s[t - d] : 0;
            __syncthreads();
            s[t] += xv;
            __syncthreads();
        }
        if (b < NB) blockHist[b * NGRAPH + g] = base + s[t] - v;
        int tot = s[511];
        __syncthreads();
        base += tot;
    }
}
__global__ void k_gscatter2(const int* __restrict__ gid, const int* __restrict__ blockHist,
                            int* __restrict__ eIdx, int E)
{
    __shared__ int h[NGRAPH];
    int t = threadIdx.x;
    h[t] = 0;
    __syncthreads();
    int i = blockIdx.x * 256 + t;
    if (i < E) {
        int g = gid[i];
        int r = atomicAdd(&h[g], 1);                 // LDS atomic: intra-block rank
        eIdx[blockHist[blockIdx.x * NGRAPH + g] + r] = i;
    }
}

// ---------------- dual-chain dense PQ GEMM: both chains in one launch ------------
__launch_bounds__(256)
__global__ void k_pq2(const ushort* __restrict__ B1, const ushort* __restrict__ B2,
                      const short* __restrict__ We, const short* __restrict__ Wn,
                      ushort* __restrict__ PQe, ushort* __restrict__ PQn,
                      int E, int eb)
{
    __shared__ __align__(16) short Ms16[64 * 136];   // 17,408 B relay
    int bb = blockIdx.x;
    const ushort* B; const short* Wb; ushort* PQ;
    if (bb < eb) { B = B1; Wb = We; PQ = PQe; }
    else { bb -= eb; B = B2; Wb = Wn; PQ = PQn; }

    const int t = threadIdx.x;
    const int e0 = bb * 64;
    const int lane = t & 63, wv = t >> 6, quad = lane >> 4, l16 = lane & 15;
    const int em = wv * 16;

    int er = e0 + em + l16; if (er >= E) er = E - 1;

    float4v acc[8];
    #pragma unroll
    for (int i = 0; i < 8; ++i) acc[i] = (float4v){0.f, 0.f, 0.f, 0.f};

    #pragma unroll
    for (int c = 0; c < 2; ++c) {
        int kb = c * 4 + quad;
        short8v a = *(const short8v*)&B[(ll)er * 64 + kb * 8];
        #pragma unroll
        for (int tn = 0; tn < 8; ++tn) {
            short8v bw = *(const short8v*)&Wb[(kb * 128 + tn * 16 + l16) * 8];
            acc[tn] = __builtin_amdgcn_mfma_f32_16x16x32_bf16(a, bw, acc[tn], 0, 0, 0);
        }
    }

    // relay acc -> bf16 LDS -> coalesced PQ store
    #pragma unroll
    for (int tn = 0; tn < 8; ++tn)
        #pragma unroll
        for (int r = 0; r < 4; ++r)
            Ms16[(em + quad * 4 + r) * 136 + tn * 16 + l16] = (short)f2bs(acc[tn][r]);
    __syncthreads();
    #pragma unroll
    for (int r = 0; r < 4; ++r) {
        int id = t + r * 256;
        int row = id >> 4, q = id & 15;
        if (e0 + row < E)
            *(uint4*)&PQ[(ll)(e0 + row) * 128 + q * 8] = *(uint4*)&Ms16[row * 136 + q * 8];
    }
}

// ---------------- dual-chain scatter-agg: one wave per 32-pair span --------------
// Round-15: span halved 64 -> 32 pairs (grid 2x: 18752 waves for 8192 slots)
// so CUs keep full wave residency and hide gather latency ACROSS waves.
// Ring back at 4 packs (round-14's deeper ring was neutral). Indices live in
// lanes 0-31 (upper half mirrors); masks use ballot bits 0..31 only.
__launch_bounds__(256)
__global__ void k_scat2(const ushort* __restrict__ PQe, const ushort* __restrict__ PQn,
                        const int2* __restrict__ prS,
                        const float* __restrict__ bme, const float* __restrict__ bmn,
                        ushort* __restrict__ agge, ushort* __restrict__ aggn,
                        ushort* __restrict__ bVe, ushort* __restrict__ bVn,
                        int* __restrict__ bDe, int* __restrict__ bDn,
                        int M, int scb)
{
    int bb = blockIdx.x;
    const ushort* PQ; const float* bm; ushort* aggb; ushort* bndVal; int* bndDst;
    if (bb < scb) { PQ = PQe; bm = bme; aggb = agge; bndVal = bVe; bndDst = bDe; }
    else { bb -= scb; PQ = PQn; bm = bmn; aggb = aggn; bndVal = bVn; bndDst = bDn; }

    const int lane = threadIdx.x & 63, wv = threadIdx.x >> 6;
    const int hl = lane & 31;
    const bool isUp = lane >= 32;
    const int sp = bb * 4 + wv;
    const int m0 = sp * 32;                      // 32-pair span
    const float bba = bm[2 * hl], bbb = bm[2 * hl + 1];
    const unsigned* PQu = (const unsigned*)PQ;   // row r: P dwords [r*64+hl], Q [r*64+32+hl]
    unsigned* aggu = (unsigned*)aggb;
    unsigned* bVu  = (unsigned*)bndVal;

    int mm = m0 + hl;                            // lanes 32-63 mirror lanes 0-31
    int2 pr = (mm < M) ? prS[mm] : make_int2(0, -1);
    int fiv = pr.x, sev = pr.y;

    int cur = __builtin_amdgcn_readlane(sev, 0);
    if (cur < 0) {
        if (lane == 0) { bndDst[2 * sp] = -1; bndDst[2 * sp + 1] = -1; }
        return;
    }

    // wave-uniform scalar masks; only bits 0..31 are used (pairs 0..31)
    unsigned long long vmask = __ballot(sev >= 0);
    int prevv = __shfl_up(sev, 1);
    unsigned long long bmask = __ballot(lane > 0 && sev != prevv);

    float sa = 0.f, sb = 0.f;
    bool headDone = false;
    auto FLUSH = [&](int nxt) {
        float ta = sa + __shfl_xor(sa, 32);
        float tb = sb + __shfl_xor(sb, 32);
        unsigned w = (unsigned)f2bs(ta) | ((unsigned)f2bs(tb) << 16);
        if (!headDone) {
            if (!isUp) bVu[(ll)(2 * sp) * 32 + hl] = w;
            if (lane == 0) bndDst[2 * sp] = cur;
            headDone = true;
        } else {
            if (!isUp) aggu[(ll)cur * 32 + hl] = w;
        }
        sa = 0.f; sb = 0.f; cur = nxt;
    };

    unsigned pu[4], qu[4];
    #pragma unroll
    for (int u = 0; u < 4; ++u) {       // prologue: packs 0..3 (pairs 0..7)
        int idx = 2 * u + (isUp ? 1 : 0);
        int fr = __shfl(fiv, idx);
        int sr = max(__shfl(sev, idx), 0);
        pu[u] = PQu[(size_t)(unsigned)fr * 64 + hl];
        qu[u] = PQu[(size_t)(unsigned)sr * 64 + 32 + hl];
    }

    for (int k0 = 0; k0 < 16; k0 += 4) {
        #pragma unroll
        for (int u = 0; u < 4; ++u) {
            int k = k0 + u;
            unsigned pw = pu[u], qw = qu[u];
            int k4 = k + 4;
            if (k4 < 16) {              // refill pack k+4 into slot u
                int idx = 2 * k4 + (isUp ? 1 : 0);
                int fr = __shfl(fiv, idx);
                int sr = max(__shfl(sev, idx), 0);
                pu[u] = PQu[(size_t)(unsigned)fr * 64 + hl];
                qu[u] = PQu[(size_t)(unsigned)sr * 64 + 32 + hl];
            }
            float pa = bs2f((ushort)(pw & 0xffffu)), pb = bs2f((ushort)(pw >> 16));
            float qa = bs2f((ushort)(qw & 0xffffu)), qb = bs2f((ushort)(qw >> 16));
            float ca = selu_f(pa + qa + bba);
            float cb = selu_f(pb + qb + bbb);
            // pair 2k (owned by lower half)
            if ((bmask >> (2 * k)) & 1ull)
                FLUSH(__builtin_amdgcn_readlane(sev, 2 * k));
            if ((vmask >> (2 * k)) & 1ull) {
                if (!isUp) { sa += ca; sb += cb; }
            }
            // pair 2k+1 (owned by upper half)
            if ((bmask >> (2 * k + 1)) & 1ull)
                FLUSH(__builtin_amdgcn_readlane(sev, 2 * k + 1));
            if ((vmask >> (2 * k + 1)) & 1ull) {
                if (isUp) { sa += ca; sb += cb; }
            }
        }
    }
    // final record
    {
        float ta = sa + __shfl_xor(sa, 32);
        float tb = sb + __shfl_xor(sb, 32);
        unsigned w = (unsigned)f2bs(ta) | ((unsigned)f2bs(tb) << 16);
        if (!headDone) {
            if (!isUp) bVu[(ll)(2 * sp) * 32 + hl] = w;
            if (lane == 0) { bndDst[2 * sp] = cur; bndDst[2 * sp + 1] = -1; }
        } else {
            if (!isUp) bVu[(ll)(2 * sp + 1) * 32 + hl] = w;
            if (lane == 0) bndDst[2 * sp + 1] = cur;
        }
    }
}

// ---------------- dual-chain boundary fixup --------------------------------------
__global__ void k_fix2(const int* __restrict__ bDe, const int* __restrict__ bDn,
                       const ushort* __restrict__ bVe, const ushort* __restrict__ bVn,
                       ushort* __restrict__ agge, ushort* __restrict__ aggn,
                       int NR, int fixb)
{
    int bb = blockIdx.x;
    const int* bndDst; const ushort* bndVal; ushort* aggb;
    if (bb < fixb) { bndDst = bDe; bndVal = bVe; aggb = agge; }
    else { bb -= fixb; bndDst = bDn; bndVal = bVn; aggb = aggn; }

    int idx = (bb * 256 + threadIdx.x) >> 6;
    int lane = threadIdx.x & 63;
    if (idx >= NR) return;
    int dst = bndDst[idx];
    if (dst < 0) return;
    int pprev = idx - 1;
    while (pprev >= 0 && bndDst[pprev] < 0) --pprev;
    if (pprev >= 0 && bndDst[pprev] == dst) return;    // not chain head
    float s = 0.f;
    for (int r = idx; r < NR; ++r) {
        int d = bndDst[r];
        if (d == dst) s += bs2f(bndVal[(ll)r * 64 + lane]);
        else if (d >= 0) break;
    }
    aggb[(ll)dst * 64 + lane] = f2bs(s);
}

// ---------------- dual-chain GRU: joint z/r accumulators, LDS-relayed ho ---------
__launch_bounds__(256)
__global__ void k_gru2(const ushort* __restrict__ agge, const ushort* __restrict__ aggn,
                       ushort* __restrict__ B1, ushort* __restrict__ B2,
                       const short* __restrict__ Gxe, const short* __restrict__ Gxn,
                       const short* __restrict__ Ghe, const short* __restrict__ Ghn,
                       const float* __restrict__ bxe, const float* __restrict__ bxn,
                       const float* __restrict__ bhe, const float* __restrict__ bhn,
                       int E, int eb)
{
    __shared__ __align__(16) short Hs[64 * 64];      // 8 KB swizzled h relay
    int bb = blockIdx.x;
    const ushort* xb; ushort* hb; const short* Gxb; const short* Ghb;
    const float* bgx; const float* bgh;
    if (bb < eb) { xb = agge; hb = B1; Gxb = Gxe; Ghb = Ghe; bgx = bxe; bgh = bhe; }
    else { bb -= eb; xb = aggn; hb = B2; Gxb = Gxn; Ghb = Ghn; bgx = bxn; bgh = bhn; }

    const int t = threadIdx.x;
    const int e0 = bb * 64;
    const int lane = t & 63, wv = t >> 6, quad = lane >> 4, l16 = lane & 15;
    const int em = wv * 16;
    int er = e0 + em + l16; if (er >= E) er = E - 1;
    const int hrow = em + l16;                       // block-local row this lane loads

    float4v zr[8], xh[4], hh[4];
    #pragma unroll
    for (int i = 0; i < 8; ++i) zr[i] = (float4v){0.f, 0.f, 0.f, 0.f};
    #pragma unroll
    for (int i = 0; i < 4; ++i) { xh[i] = (float4v){0.f,0.f,0.f,0.f}; hh[i] = (float4v){0.f,0.f,0.f,0.f}; }

    #pragma unroll
    for (int c = 0; c < 2; ++c) {
        int kb = c * 4 + quad;
        short8v a_x = *(const short8v*)&xb[(ll)er * 64 + kb * 8];
        short8v a_h = *(const short8v*)&hb[(ll)er * 64 + kb * 8];
        // stage h fragment into swizzled LDS (intra-wave rows only)
        *(short8v*)&Hs[hrow * 64 + ((kb ^ (hrow & 7)) << 3)] = a_h;
        #pragma unroll
        for (int tn = 0; tn < 8; ++tn) {    // z,r gates: x and h into one acc
            short8v b_x = *(const short8v*)&Gxb[(kb * 192 + tn * 16 + l16) * 8];
            zr[tn] = __builtin_amdgcn_mfma_f32_16x16x32_bf16(a_x, b_x, zr[tn], 0, 0, 0);
            short8v b_h = *(const short8v*)&Ghb[(kb * 192 + tn * 16 + l16) * 8];
            zr[tn] = __builtin_amdgcn_mfma_f32_16x16x32_bf16(a_h, b_h, zr[tn], 0, 0, 0);
        }
        #pragma unroll
        for (int tn = 0; tn < 4; ++tn) {    // hh gate: keep x and h separate
            short8v b_x = *(const short8v*)&Gxb[(kb * 192 + (8 + tn) * 16 + l16) * 8];
            xh[tn] = __builtin_amdgcn_mfma_f32_16x16x32_bf16(a_x, b_x, xh[tn], 0, 0, 0);
            short8v b_h = *(const short8v*)&Ghb[(kb * 192 + (8 + tn) * 16 + l16) * 8];
            hh[tn] = __builtin_amdgcn_mfma_f32_16x16x32_bf16(a_h, b_h, hh[tn], 0, 0, 0);
        }
    }

    // hoisted biases
    float bz[4], br_[4], bxh[4], bhh[4];
    #pragma unroll
    for (int j = 0; j < 4; ++j) {
        int d = j * 16 + l16;
        bz[j]  = bgx[d] + bgh[d];
        br_[j] = bgx[64 + d] + bgh[64 + d];
        bxh[j] = bgx[128 + d];
        bhh[j] = bgh[128 + d];
    }

    #pragma unroll
    for (int r = 0; r < 4; ++r) {
        int rowl = em + quad * 4 + r;       // block-local (within this wave's 16 rows)
        int e = e0 + rowl;
        if (e >= E) continue;
        #pragma unroll
        for (int j = 0; j < 4; ++j) {
            int d = j * 16 + l16;
            float z  = fsigmoid(zr[j][r] + bz[j]);
            float rr = fsigmoid(zr[4 + j][r] + br_[j]);
            float cc = ftanh(xh[j][r] + bxh[j] + rr * (hh[j][r] + bhh[j]));
            float ho = bs2f((ushort)Hs[rowl * 64 + ((((d >> 3) ^ (rowl & 7)) << 3) | (d & 7))]);
            hb[(ll)e * 64 + d] = f2bs(z * ho + (1.f - z) * cc);
        }
    }
}

// ---------------- span-parallel pooling over gid-sorted edges --------------------
__launch_bounds__(256)
__global__ void k_pool2(const ushort* __restrict__ lsb, const ushort* __restrict__ nsb,
                        const int* __restrict__ eIdx, const int* __restrict__ gid,
                        float* __restrict__ pooled, int E)
{
    const int t = threadIdx.x, lane = t & 63, wv = t >> 6;
    const int span = blockIdx.x * 2 + (wv >> 1);
    const int colhalf = wv & 1;
    const int s0 = span * 64;
    if (s0 >= E) return;

    int idx = s0 + lane;
    int ei = (idx < E) ? eIdx[idx] : 0;
    int gv = (idx < E) ? gid[ei] : -1;
    const ushort* src = colhalf ? nsb : lsb;   // node pad cols are exact zeros
    const int cb = colhalf ? 64 : 0;

    float pv[4];
    #pragma unroll
    for (int u = 0; u < 4; ++u) {
        int e = __shfl(ei, u);
        pv[u] = bs2f(src[(ll)e * 64 + lane]);
    }

    int curg = __shfl(gv, 0);                  // lane 0 always valid (s0 < E)
    float acc = 0.f;
    for (int i0 = 0; i0 < 64; i0 += 4) {
        #pragma unroll
        for (int u = 0; u < 4; ++u) {
            int i = i0 + u;
            int g = __shfl(gv, i);
            float v = pv[u];
            int i4 = i + 4;
            if (i4 < 64) {                     // prefetch ring refill
                int e = __shfl(ei, i4);
                pv[u] = bs2f(src[(ll)e * 64 + lane]);
            }
            if (g >= 0) {
                if (g != curg) {
                    atomicAdd(&pooled[curg * 128 + cb + lane], acc);
                    curg = g; acc = 0.f;
                }
                acc += v;
            }
        }
    }
    atomicAdd(&pooled[curg * 128 + cb + lane], acc);
}

// ---------------- fused per-graph MLP: typed body, 4-way k-split, 16 waves -------
template <typename T>
__device__ __forceinline__ void mlp_body(const float* __restrict__ pooled,
                                         const T* __restrict__ W1, const T* __restrict__ b1,
                                         const T* __restrict__ W2, const T* __restrict__ b2,
                                         const T* __restrict__ W3, const T* __restrict__ b3,
                                         void* __restrict__ out, int isf)
{
    __shared__ float pooledS[128];
    __shared__ float h1s[256];
    __shared__ float ps[4][256];
    __shared__ float red[256];
    const int g = blockIdx.x, t = threadIdx.x;
    const int j = t & 255, s = t >> 8;          // 1024 threads: 4 k-splits x 256 cols

    if (t < 128) pooledS[t] = pooled[g * 128 + t];
    __syncthreads();

    {   // layer 1: K = 123, split 4 x 31
        int k0 = s * 31, k1 = min(64 + DNODE, k0 + 31);
        float a = 0.f;
        #pragma unroll 4
        for (int k = k0; k < k1; ++k)
            a = fmaf(pooledS[k], ldT<T>(W1, (ll)k * 256 + j), a);
        ps[s][j] = a;
    }
    __syncthreads();
    if (t < 256) {
        float a1 = ldT<T>(b1, t) + ps[0][t] + ps[1][t] + ps[2][t] + ps[3][t];
        h1s[t] = selu_f(a1);
    }
    __syncthreads();

    {   // layer 2: K = 256, split 4 x 64
        int k0 = s * 64;
        float a = 0.f;
        #pragma unroll 8
        for (int k = k0; k < k0 + 64; ++k)
            a = fmaf(h1s[k], ldT<T>(W2, (ll)k * 256 + j), a);
        ps[s][j] = a;
    }
    __syncthreads();
    if (t < 256) {
        float a2 = ldT<T>(b2, t) + ps[0][t] + ps[1][t] + ps[2][t] + ps[3][t];
        red[t] = selu_f(a2) * ldT<T>(W3, t);
    }
    __syncthreads();
    for (int sdt = 128; sdt > 0; sdt >>= 1) {
        if (t < sdt) red[t] += red[t + sdt];
        __syncthreads();
    }
    if (t == 0) {
        float o = red[0] + ldT<T>(b3, 0);
        if (isf) ((float*)out)[g] = o;
        else     ((bf16*)out)[g] = __float2bfloat16(o);
    }
}
__launch_bounds__(1024)
__global__ void k_mlpall(const float* __restrict__ pooled,
                         const void* __restrict__ W1, const void* __restrict__ b1,
                         const void* __restrict__ W2, const void* __restrict__ b2,
                         const void* __restrict__ W3, const void* __restrict__ b3,
                         void* __restrict__ out, const int* __restrict__ dflag)
{
    const int isf = *dflag;                     // hoisted dtype branch
    if (isf) mlp_body<float>(pooled, (const float*)W1, (const float*)b1,
                             (const float*)W2, (const float*)b2,
                             (const float*)W3, (const float*)b3, out, 1);
    else     mlp_body<bf16> (pooled, (const bf16*)W1, (const bf16*)b1,
                             (const bf16*)W2, (const bf16*)b2,
                             (const bf16*)W3, (const bf16*)b3, out, 0);
}

extern "C" void kernel_launch(void* const* d_in, const int* in_sizes, int n_in,
                              void* d_out, int out_size, void* d_ws, size_t ws_size,
                              hipStream_t stream)
{
    const void* graph_state = d_in[0];
    const void* node_state  = d_in[1];
    const int*  first   = (const int*)d_in[2];
    const int*  second  = (const int*)d_in[3];
    const int*  gid     = (const int*)d_in[4];
    const void* W_msg  = d_in[6];
    const void* b_msg  = d_in[7];
    const void* Wx_e   = d_in[8];
    const void* Wh_e   = d_in[9];
    const void* bx_e   = d_in[10];
    const void* bh_e   = d_in[11];
    const void* W_nmsg = d_in[12];
    const void* b_nmsg = d_in[13];
    const void* Wx_n   = d_in[14];
    const void* Wh_n   = d_in[15];
    const void* bx_n   = d_in[16];
    const void* bh_n   = d_in[17];
    const void* W1 = d_in[18];
    const void* b1 = d_in[19];
    const void* W2 = d_in[20];
    const void* b2 = d_in[21];
    const void* W3 = d_in[22];
    const void* b3 = d_in[23];

    const int E = in_sizes[0] / 64;      // 100000
    const int M = in_sizes[2];           // 300000
    const int eb   = (E + 63) / 64;      // per-chain k_pq2 / k_gru2 blocks
    const int nsp  = (M + 31) / 32;      // 32-pair spans
    const int scb  = (nsp + 3) / 4;      // per-chain k_scat2 blocks (4 waves each)
    const int NR   = 2 * scb * 4;        // boundary records per chain (covers tail)
    const int fixb = (NR * 64 + 255) / 256;
    const int psp  = (E + 63) / 64;      // pooling spans
    const int plb  = (psp + 1) / 2;      // k_pool2 blocks (2 spans each)

    // ---- workspace layout (~110 MB) ----
    ushort* B1    = (ushort*)d_ws;                  // bf16 link state [E*64]
    ushort* B2    = B1 + (size_t)E * 64;            // bf16 node state [E*64]
    ushort* agge  = B2 + (size_t)E * 64;            // bf16 link agg [E*64]
    ushort* aggn  = agge + (size_t)E * 64;          // bf16 node agg [E*64]
    ushort* PQe   = aggn + (size_t)E * 64;          // bf16 [E*128]
    ushort* PQn   = PQe + (size_t)E * 128;          // bf16 [E*128]
    int2*   prS   = (int2*)(PQn + (size_t)E * 128); // packed (first,second) [M]
    ushort* bVe   = (ushort*)(prS + M);             // [NR*64]
    ushort* bVn   = bVe + (size_t)NR * 64;          // [NR*64]
    int*    bDe   = (int*)(bVn + (size_t)NR * 64);
    int*    bDn   = bDe + NR;
    short*  sb    = (short*)(bDn + NR);
    size_t so = 0;
    short* Wpq_e = sb + so; so += 8192;
    short* Wpq_n = sb + so; so += 8192;
    short* Gxb_e = sb + so; so += 12288;
    short* Ghb_e = sb + so; so += 12288;
    short* Gxb_n = sb + so; so += 12288;
    short* Ghb_n = sb + so; so += 12288;
    float* fb = (float*)(sb + so);
    size_t fo = 0;
    float* bm_e  = fb + fo; fo += 64;
    float* bm_n  = fb + fo; fo += 64;
    float* bgx_e = fb + fo; fo += 192;
    float* bgh_e = fb + fo; fo += 192;
    float* bgx_n = fb + fo; fo += 192;
    float* bgh_n = fb + fo; fo += 192;
    int* dflag = (int*)(fb + fo);
    // gid-sort scratch (static indices)
    int* gcnt = dflag + 1;                 // [256]
    int* gpos = gcnt + 256;                // [256]
    int* gOff = gcnt + 512;                // [257]
    int* eIdx = gcnt + 769;                // [E]
    // overlays: sort scratch in agge (free before MP loop); blockHist in PQe
    // (free before MP loop); pooled in PQe (free after MP loop)
    int* cnt   = (int*)agge;
    int* bsum  = cnt + E;
    int* ebsum = bsum + 512;
    int* blockHist = (int*)PQe;            // [NB_E * NGRAPH]
    float* pooled = (float*)PQe;           // [NGRAPH*128] fp32 (post-MP)

    // ---- dtype detect (+ zero gid-sort counters) + fused init/prep ----
    k_detect<<<1, 512, 0, stream>>>((const ushort*)graph_state, dflag, gcnt);
    const int ebi = (E * 64 + 255) / 256;
    k_prep_all<<<2 * ebi + 64 + 192 + 1, 256, 0, stream>>>(
        graph_state, node_state, B1, B2,
        W_msg, W_nmsg, Wx_e, Wh_e, Wx_n, Wh_n,
        b_msg, b_nmsg, bx_e, bh_e, bx_n, bh_n,
        Wpq_e, Wpq_n, Gxb_e, Ghb_e, Gxb_n, Ghb_n,
        bm_e, bm_n, bgx_e, bgh_e, bgx_n, bgh_n, E, dflag);

    // ---- counting sort by `second` -> prS (scratch overlays agge) ----
    const int NB = (E + 255) / 256;
    hipMemsetAsync(cnt, 0, (size_t)E * sizeof(int), stream);
    k_hist<<<(M + 255) / 256, 256, 0, stream>>>(second, cnt, M);
    k_scan_block<<<NB, 256, 0, stream>>>(cnt, bsum, E);
    k_scan_top<<<1, 512, 0, stream>>>(bsum, ebsum, NB);
    k_scan_add<<<NB, 256, 0, stream>>>(cnt, ebsum, E);
    k_scatter<<<(M + 255) / 256, 256, 0, stream>>>(first, second, cnt, prS, M);

    // ---- one-time agg zeroing (agge|aggn contiguous; sort scratch now dead).
    hipMemsetAsync(agge, 0, (size_t)2 * E * 64 * sizeof(ushort), stream);

    // ---- counting sort of edges by gid -> eIdx (atomic-free scatter) ----
    k_ghist2<<<NB, 256, 0, stream>>>(gid, gcnt, blockHist, E);
    k_gscan<<<1, 256, 0, stream>>>(gcnt, gOff, gpos);
    k_gbase2<<<NGRAPH, 512, 0, stream>>>(gOff, blockHist, NB);
    k_gscatter2<<<NB, 256, 0, stream>>>(gid, blockHist, eIdx, E);

    // ---- message passing: link+node chains merged per dispatch (independent) ----
    for (int it = 0; it < 4; ++it) {
        k_pq2  <<<2 * eb,   256, 0, stream>>>(B1, B2, Wpq_e, Wpq_n, PQe, PQn, E, eb);
        k_scat2<<<2 * scb,  256, 0, stream>>>(PQe, PQn, prS, bm_e, bm_n,
                                              agge, aggn, bVe, bVn, bDe, bDn, M, scb);
        k_fix2 <<<2 * fixb, 256, 0, stream>>>(bDe, bDn, bVe, bVn, agge, aggn, NR, fixb);
        k_gru2 <<<2 * eb,   256, 0, stream>>>(agge, aggn, B1, B2,
                                              Gxb_e, Gxb_n, Ghb_e, Ghb_n,
                                              bgx_e, bgx_n, bgh_e, bgh_n, E, eb);
    }

    // ---- readout: span-parallel pool + fused per-graph MLP ----
    hipMemsetAsync(pooled, 0, (size_t)NGRAPH * 128 * sizeof(float), stream);
    k_pool2<<<plb, 256, 0, stream>>>(B1, B2, eIdx, gid, pooled, E);
    k_mlpall<<<NGRAPH, 1024, 0, stream>>>(pooled, W1, b1, W2, b2, W3, b3, d_out, dflag);
}